// Round 1
// baseline (122.646 us; speedup 1.0000x reference)
//
#include <hip/hip_runtime.h>
#include <math.h>

#define HW 4096
#define NB 4
#define LCAP 64

typedef unsigned short ushort_t;
typedef unsigned int uint_t;
typedef __attribute__((ext_vector_type(8))) short s8v;      // 8 bf16 (4 VGPRs)
typedef __attribute__((ext_vector_type(4))) float f32x4;    // MFMA acc

__device__ __forceinline__ ushort_t f2bf(float f) {
  uint_t u = __float_as_uint(f);
  u = (u + 0x7fffu + ((u >> 16) & 1u)) >> 16;
  return (ushort_t)u;
}
__device__ __forceinline__ float bf2f(ushort_t h) {
  uint_t u = ((uint_t)h) << 16;
  return __uint_as_float(u);
}

// Shared dot: bitwise-identical in maxscan and topk (soundness of the tau bound).
__device__ __forceinline__ float dot8(float4 klo, float4 khi, const float* qp) {
  float4 q0 = *(const float4*)qp;
  float4 q1 = *(const float4*)(qp + 4);
  float e = klo.x * q0.x;
  e = fmaf(klo.y, q0.y, e);
  e = fmaf(klo.z, q0.z, e);
  e = fmaf(klo.w, q0.w, e);
  e = fmaf(khi.x, q1.x, e);
  e = fmaf(khi.y, q1.y, e);
  e = fmaf(khi.z, q1.z, e);
  e = fmaf(khi.w, q1.w, e);
  return e;
}
__device__ __forceinline__ float dot8v(float4 klo, float4 khi, float4 q0, float4 q1) {
  float e = klo.x * q0.x;
  e = fmaf(klo.y, q0.y, e);
  e = fmaf(klo.z, q0.z, e);
  e = fmaf(klo.w, q0.w, e);
  e = fmaf(khi.x, q1.x, e);
  e = fmaf(khi.y, q1.y, e);
  e = fmaf(khi.z, q1.z, e);
  e = fmaf(khi.w, q1.w, e);
  return e;
}

// ---------------- Kernel A: q/k 1x1 convs (+ fused weight transpose) ----------
// grid (64, 4), block 256. red padded to 17-float rows (conflict-free).
__global__ __launch_bounds__(256) void qk_kernel(
    const float* __restrict__ x, const float* __restrict__ qw,
    const float* __restrict__ qb, const float* __restrict__ kw,
    const float* __restrict__ kb, const float* __restrict__ w,
    float* __restrict__ q_t, float* __restrict__ k_t, float* __restrict__ wt) {
  __shared__ float red[4][64][17];
  __shared__ float sqwT[512], skwT[512];
  int b = blockIdx.y;
  int sl = threadIdx.x & 63;
  int cg = threadIdx.x >> 6;
  int s = blockIdx.x * 64 + sl;

  {
    int bid = blockIdx.y * 64 + blockIdx.x;
    int gid = bid * 256 + threadIdx.x;
    if (gid < 64 * 64 * 9) {
      int o = gid / 576, rem = gid % 576, c = rem / 9, k = rem % 9;
      wt[(k * 64 + c) * 64 + o] = w[gid];
    }
  }

  for (int i = threadIdx.x; i < 512; i += 256) {
    int c = i >> 3, d = i & 7;
    sqwT[i] = qw[d * 64 + c];
    skwT[i] = kw[d * 64 + c];
  }
  __syncthreads();

  float qa[8], ka[8];
#pragma unroll
  for (int d = 0; d < 8; ++d) { qa[d] = 0.f; ka[d] = 0.f; }
  const float* xp = x + ((size_t)b * 64 + cg * 16) * HW + s;
#pragma unroll
  for (int c = 0; c < 16; ++c) {
    float xv = xp[(size_t)c * HW];
    int cc = cg * 16 + c;
    const float4 qw0 = *(const float4*)&sqwT[cc * 8];
    const float4 qw1 = *(const float4*)&sqwT[cc * 8 + 4];
    const float4 kw0 = *(const float4*)&skwT[cc * 8];
    const float4 kw1 = *(const float4*)&skwT[cc * 8 + 4];
    qa[0] = fmaf(qw0.x, xv, qa[0]); qa[1] = fmaf(qw0.y, xv, qa[1]);
    qa[2] = fmaf(qw0.z, xv, qa[2]); qa[3] = fmaf(qw0.w, xv, qa[3]);
    qa[4] = fmaf(qw1.x, xv, qa[4]); qa[5] = fmaf(qw1.y, xv, qa[5]);
    qa[6] = fmaf(qw1.z, xv, qa[6]); qa[7] = fmaf(qw1.w, xv, qa[7]);
    ka[0] = fmaf(kw0.x, xv, ka[0]); ka[1] = fmaf(kw0.y, xv, ka[1]);
    ka[2] = fmaf(kw0.z, xv, ka[2]); ka[3] = fmaf(kw0.w, xv, ka[3]);
    ka[4] = fmaf(kw1.x, xv, ka[4]); ka[5] = fmaf(kw1.y, xv, ka[5]);
    ka[6] = fmaf(kw1.z, xv, ka[6]); ka[7] = fmaf(kw1.w, xv, ka[7]);
  }
#pragma unroll
  for (int d = 0; d < 8; ++d) {
    red[cg][sl][d] = qa[d];
    red[cg][sl][8 + d] = ka[d];
  }
  __syncthreads();

#pragma unroll
  for (int r = 0; r < 4; ++r) {
    int f = r * 256 + threadIdx.x;
    int slf = f >> 4, dd = f & 15;
    float sum = red[0][slf][dd] + red[1][slf][dd] + red[2][slf][dd] + red[3][slf][dd];
    int ss_ = blockIdx.x * 64 + slf;
    if (dd < 8)
      q_t[((size_t)b * HW + ss_) * 8 + dd] = sum + qb[dd];
    else
      k_t[((size_t)b * HW + ss_) * 8 + (dd - 8)] = sum + kb[dd - 8];
  }
}

// ---------------- Kernel B: fused maxscan (1024 blocks) + gemm (2304 blocks) --
// maxscan: per-64-chunk maxima, 4 t's per lane (bit-identical dot chains).
// gemm: y[b,k,s,o] = sum_c x[b,c,s]*wt[k][c][o] via MFMA bf16.
//   X split into bf16 hi+lo (2 MFMA chains), W single bf16; y stored bf16 as
//   before. Error ~1.45x prior kernel (which passed) -- top-k path untouched.
__global__ __launch_bounds__(256) void mid_kernel(
    const float* __restrict__ q_t, const float* __restrict__ k_t,
    const float* __restrict__ x, const float* __restrict__ wt,
    float* __restrict__ maxima, ushort_t* __restrict__ y) {
  __shared__ __align__(16) float smem[8192];  // 32 KB union
  int blk = blockIdx.x;
  int tid = threadIdx.x;

  if (blk < 1024) {
    // ---- maxscan task (unchanged) ----
    float* qs = smem;  // 512 floats
    int b = blk >> 8;
    int rem = blk & 255;
    int ch = rem >> 2;
    int tg = rem & 3;
    int lane = tid & 63;
    int w = tid >> 6;
    int t0 = tg * 1024 + w * 256 + 4 * lane;

    const float* kp = k_t + ((size_t)b * HW + t0) * 8;
    float4 ka0 = *(const float4*)(kp);      float4 ka1 = *(const float4*)(kp + 4);
    float4 kb0 = *(const float4*)(kp + 8);  float4 kb1 = *(const float4*)(kp + 12);
    float4 kc0 = *(const float4*)(kp + 16); float4 kc1 = *(const float4*)(kp + 20);
    float4 kd0 = *(const float4*)(kp + 24); float4 kd1 = *(const float4*)(kp + 28);

    if (tid < 128)
      *(float4*)&qs[tid * 4] =
          *(const float4*)&q_t[((size_t)b * HW + ch * 64) * 8 + tid * 4];
    __syncthreads();

    float m0 = -INFINITY, m1 = -INFINITY, m2 = -INFINITY, m3 = -INFINITY;
#pragma unroll 4
    for (int i = 0; i < 64; ++i) {
      float4 q0 = *(const float4*)&qs[i * 8];
      float4 q1 = *(const float4*)&qs[i * 8 + 4];
      m0 = fmaxf(m0, dot8v(ka0, ka1, q0, q1));
      m1 = fmaxf(m1, dot8v(kb0, kb1, q0, q1));
      m2 = fmaxf(m2, dot8v(kc0, kc1, q0, q1));
      m3 = fmaxf(m3, dot8v(kd0, kd1, q0, q1));
    }
    *(float4*)&maxima[((size_t)b * 64 + ch) * HW + t0] =
        make_float4(m0, m1, m2, m3);
  } else {
    // ---- gemm task: 64x64 tile, MFMA bf16 ----
    // LDS tiles, K(=c)-contiguous rows, stride 72 u16 (144B, 16B-aligned rows):
    //   Xh/Xl: [s][c] hi/lo bf16 of x^T tile; Wb: [o][c] bf16 of wt^T tile.
    ushort_t* Xh = (ushort_t*)smem;        // 64*72 u16 = 9216 B
    ushort_t* Xl = Xh + 64 * 72;           // 9216 B
    ushort_t* Wb = Xl + 64 * 72;           // 9216 B  (total 27648 <= 32768)
    int task = blk - 1024;    // 0..2303
    int b = task / 576;
    int rem = task % 576;
    int kk = rem / 64;
    int s0 = (rem % 64) * 64;

    {
      // unit mapping spreads c-quads across low lane bits -> ~4-way LDS write
      // conflicts while keeping 128B-coalesced global loads.
      int sq = (tid & 7) | ((tid >> 3) & 8);   // s-/o-quad 0..15
      int cq = ((tid >> 3) & 7) | ((tid >> 4) & 8);  // c-quad 0..15
      int q4 = sq * 4;

      const float* xp = x + ((size_t)b * 64 + cq * 4) * HW + s0 + q4;
      float4 r0 = *(const float4*)(xp);
      float4 r1 = *(const float4*)(xp + HW);
      float4 r2 = *(const float4*)(xp + 2 * HW);
      float4 r3 = *(const float4*)(xp + 3 * HW);
      float c0[4] = {r0.x, r0.y, r0.z, r0.w};
      float c1[4] = {r1.x, r1.y, r1.z, r1.w};
      float c2[4] = {r2.x, r2.y, r2.z, r2.w};
      float c3[4] = {r3.x, r3.y, r3.z, r3.w};
#pragma unroll
      for (int j = 0; j < 4; ++j) {
        ushort4 hh, ll;
        hh.x = f2bf(c0[j]); ll.x = f2bf(c0[j] - bf2f(hh.x));
        hh.y = f2bf(c1[j]); ll.y = f2bf(c1[j] - bf2f(hh.y));
        hh.z = f2bf(c2[j]); ll.z = f2bf(c2[j] - bf2f(hh.z));
        hh.w = f2bf(c3[j]); ll.w = f2bf(c3[j] - bf2f(hh.w));
        *(ushort4*)&Xh[(q4 + j) * 72 + cq * 4] = hh;
        *(ushort4*)&Xl[(q4 + j) * 72 + cq * 4] = ll;
      }

      const float* wp = wt + kk * 4096 + (cq * 4) * 64 + q4;  // wt[kk][c][o]
      float4 w0 = *(const float4*)(wp);
      float4 w1 = *(const float4*)(wp + 64);
      float4 w2 = *(const float4*)(wp + 128);
      float4 w3 = *(const float4*)(wp + 192);
      float d0[4] = {w0.x, w0.y, w0.z, w0.w};
      float d1[4] = {w1.x, w1.y, w1.z, w1.w};
      float d2[4] = {w2.x, w2.y, w2.z, w2.w};
      float d3[4] = {w3.x, w3.y, w3.z, w3.w};
#pragma unroll
      for (int j = 0; j < 4; ++j) {
        ushort4 hh;
        hh.x = f2bf(d0[j]); hh.y = f2bf(d1[j]);
        hh.z = f2bf(d2[j]); hh.w = f2bf(d3[j]);
        *(ushort4*)&Wb[(q4 + j) * 72 + cq * 4] = hh;
      }
    }
    __syncthreads();

    // wave w computes s-rows [16w,16w+16) x all 64 o.
    // A[m=s][k=c]: lane holds A[l&15][8*(l>>4)+i]; B[k=c][n=o]: B[8*(l>>4)+i][l&15].
    // D: col(o)=l&15, row(s)=4*(l>>4)+reg  [guide Sec.3, m89].
    int w = tid >> 6;
    int lr = tid & 15;
    int lg = (tid & 63) >> 4;
    f32x4 acc0 = {0.f, 0.f, 0.f, 0.f};
    f32x4 acc1 = acc0, acc2 = acc0, acc3 = acc0;
#pragma unroll
    for (int ks = 0; ks < 2; ++ks) {
      int ko = ks * 32 + lg * 8;
      s8v ah = *(const s8v*)&Xh[(w * 16 + lr) * 72 + ko];
      s8v al = *(const s8v*)&Xl[(w * 16 + lr) * 72 + ko];
      s8v b0 = *(const s8v*)&Wb[(0 + lr) * 72 + ko];
      s8v b1 = *(const s8v*)&Wb[(16 + lr) * 72 + ko];
      s8v b2 = *(const s8v*)&Wb[(32 + lr) * 72 + ko];
      s8v b3 = *(const s8v*)&Wb[(48 + lr) * 72 + ko];
      acc0 = __builtin_amdgcn_mfma_f32_16x16x32_bf16(ah, b0, acc0, 0, 0, 0);
      acc1 = __builtin_amdgcn_mfma_f32_16x16x32_bf16(ah, b1, acc1, 0, 0, 0);
      acc2 = __builtin_amdgcn_mfma_f32_16x16x32_bf16(ah, b2, acc2, 0, 0, 0);
      acc3 = __builtin_amdgcn_mfma_f32_16x16x32_bf16(ah, b3, acc3, 0, 0, 0);
      acc0 = __builtin_amdgcn_mfma_f32_16x16x32_bf16(al, b0, acc0, 0, 0, 0);
      acc1 = __builtin_amdgcn_mfma_f32_16x16x32_bf16(al, b1, acc1, 0, 0, 0);
      acc2 = __builtin_amdgcn_mfma_f32_16x16x32_bf16(al, b2, acc2, 0, 0, 0);
      acc3 = __builtin_amdgcn_mfma_f32_16x16x32_bf16(al, b3, acc3, 0, 0, 0);
    }
    __syncthreads();  // all waves done reading Xh/Xl/Wb

    // pack to LDS [s][o] bf16 (stride 72), then 16B-coalesced global stores
    ushort_t* Ly = (ushort_t*)smem;
#pragma unroll
    for (int r = 0; r < 4; ++r) {
      int s = w * 16 + lg * 4 + r;
      Ly[s * 72 + 0 + lr]  = f2bf(acc0[r]);
      Ly[s * 72 + 16 + lr] = f2bf(acc1[r]);
      Ly[s * 72 + 32 + lr] = f2bf(acc2[r]);
      Ly[s * 72 + 48 + lr] = f2bf(acc3[r]);
    }
    __syncthreads();

    ushort_t* yp = y + ((size_t)(b * 9 + kk) * HW + s0) * 64;
#pragma unroll
    for (int it = 0; it < 2; ++it) {
      int f = it * 2048 + tid * 8;
      int s = f >> 6, o = f & 63;
      *(uint4*)&yp[(size_t)s * 64 + o] = *(const uint4*)&Ly[s * 72 + o];
    }
  }
}

// ---------------- Kernel C: fused tau + chunk-skip topk + gather + epilogue --
// grid (256, 4): block = 4 waves x 4 t's = 16 t's (= output j's).
__global__ __launch_bounds__(256) void topk_gather_kernel(
    const float* __restrict__ q_t, const float* __restrict__ k_t,
    const float* __restrict__ maxima, const ushort_t* __restrict__ y,
    const float* __restrict__ bias, const float* __restrict__ gamma,
    const float* __restrict__ x, float* __restrict__ out) {
  __shared__ float ldsM[64 * 17];  // [ch][16 t + pad]
  __shared__ int sArr[4][LCAP];
  __shared__ float eArr[4][LCAP];
  __shared__ int idxl[4][9];
  __shared__ float T[64 * 17];     // [o][16 j + pad]
  int b = blockIdx.y;
  int lane = threadIdx.x & 63;
  int w = threadIdx.x >> 6;
  int t0 = blockIdx.x * 16;

  // stage maxima tile [64 ch][16 t] (64B coalesced granules)
#pragma unroll
  for (int it = 0; it < 4; ++it) {
    int idx = it * 256 + threadIdx.x;
    int ch = idx >> 4, dt = idx & 15;
    ldsM[ch * 17 + dt] = maxima[((size_t)b * 64 + ch) * HW + t0 + dt];
  }
  __syncthreads();

  float g = gamma[0];
  float bs = bias[lane];
  const ushort_t* yb = y + (size_t)b * 9 * HW * 64;

#pragma unroll 1
  for (int ti = 0; ti < 4; ++ti) {
    int jl = w * 4 + ti;  // 0..15
    int t = t0 + jl;

    const float* kp = k_t + ((size_t)b * HW + t) * 8;
    float4 klo = *(const float4*)kp;
    float4 khi = *(const float4*)(kp + 4);

    float val = ldsM[lane * 17 + jl];
    float keepmax = val;
    float tauv = -INFINITY;
#pragma unroll
    for (int r = 0; r < 9; ++r) {
      float wmax = val;
#pragma unroll
      for (int off = 1; off < 64; off <<= 1)
        wmax = fmaxf(wmax, __shfl_xor(wmax, off, 64));
      tauv = wmax;
      unsigned long long m = __ballot(val == wmax);
      if (lane == (int)__builtin_ctzll(m)) val = -INFINITY;
    }

    unsigned long long mask = __ballot(keepmax >= tauv);
    int cnt = 0;
    while (mask) {
      int p = (int)__builtin_ctzll(mask);
      mask &= mask - 1;
      int s = p * 64 + lane;
      float e = dot8(klo, khi, q_t + ((size_t)b * HW + s) * 8);
      bool keep = e >= tauv;
      unsigned long long km = __ballot(keep);
      if (keep) {
        int pos = cnt + (int)__popcll(km & ((1ull << lane) - 1ull));
        if (pos < LCAP) { sArr[w][pos] = s; eArr[w][pos] = e; }
      }
      cnt += (int)__popcll(km);
    }
    if (cnt > LCAP) cnt = LCAP;

    float em = -INFINITY; int sm = 0x7fffffff;
    if (lane < cnt) { em = eArr[w][lane]; sm = sArr[w][lane]; }
    int rank = 0;
    for (int i = 0; i < cnt; ++i) {
      float ei = eArr[w][i];
      int si = sArr[w][i];
      rank += ((ei > em) || (ei == em && si < sm)) ? 1 : 0;
    }
    bool sel = (lane < cnt) && (rank < 9);
    unsigned long long smask = __ballot(sel);
    int pos = (int)__popcll(smask & ((1ull << lane) - 1ull));
    if (sel) idxl[w][pos] = sm;  // ascending-s order

    // gather this t: lane = o
    float acc = bs;
#pragma unroll
    for (int k = 0; k < 9; ++k) {
      int p9 = idxl[w][k];
      acc += bf2f(yb[((size_t)k * HW + p9) * 64 + lane]);
    }
    T[lane * 17 + jl] = g * fmaxf(acc, 0.f);
  }
  __syncthreads();

  // epilogue: out[b,o,t0+jl] = T[o][jl] + x[b,o,t0+jl], 64B granules
  for (int f = threadIdx.x; f < 1024; f += 256) {
    int o = f >> 4, jl = f & 15;
    size_t gi = ((size_t)b * 64 + o) * HW + t0 + jl;
    out[gi] = T[o * 17 + jl] + x[gi];
  }
}

extern "C" void kernel_launch(void* const* d_in, const int* in_sizes, int n_in,
                              void* d_out, int out_size, void* d_ws, size_t ws_size,
                              hipStream_t stream) {
  const float* x = (const float*)d_in[0];
  const float* qw = (const float*)d_in[1];
  const float* qb = (const float*)d_in[2];
  const float* kw = (const float*)d_in[3];
  const float* kb = (const float*)d_in[4];
  const float* gamma = (const float*)d_in[5];
  const float* weight = (const float*)d_in[6];
  const float* bias = (const float*)d_in[7];
  float* out = (float*)d_out;

  char* ws = (char*)d_ws;
  float* q_t = (float*)(ws);                  //   524288 -> 524288
  float* k_t = (float*)(ws + 524288);         //   524288 -> 1048576
  float* wt = (float*)(ws + 1048576);         //   147456 -> 1196032
  float* maxima = (float*)(ws + 1196032);     //  4194304 -> 5390336
  ushort_t* y = (ushort_t*)(ws + 5390336);    // 18874368 -> 24264704

  hipLaunchKernelGGL(qk_kernel, dim3(64, 4), dim3(256), 0, stream,
                     x, qw, qb, kw, kb, weight, q_t, k_t, wt);
  hipLaunchKernelGGL(mid_kernel, dim3(1024 + 2304), dim3(256), 0, stream,
                     q_t, k_t, x, wt, maxima, y);
  hipLaunchKernelGGL(topk_gather_kernel, dim3(256, 4), dim3(256), 0, stream,
                     q_t, k_t, maxima, y, bias, gamma, x, out);
}